// Round 6
// baseline (277.423 us; speedup 1.0000x reference)
//
#include <hip/hip_runtime.h>
#include <hip/hip_bf16.h>

// Problem: out = x @ W_eff^T + bias   (TOKENS=2048, N=4096, M=K=4096)
// W_eff = rownorm-rescaled Givens-rotated W; pairs are (2s,2s+1) adjacent,
// so row pair (2s,2s+1) and col pair (2t,2t+1) are closed 2x2 blocks.
//
// Norm identity: right rotations are orthogonal on the column space ->
// preserve each row's norm. So ||Wp row|| needs only ||w0||^2, ||w1||^2,
// <w0,w1> (3 reduced scalars), not the rotated data.
//
// Journal:
//  R1 (good): 128x128 BK=64 dbuf + counted vmcnt(8) + T2 both-sides swizzle:
//     gemm 95.3 -> 71.4 us (962 TF, MfmaUtil 40%, bank conflicts 0).
//  R2 (FAILED): phase split w/ lgkm(0) drains between ds_read and MFMA:
//     107 us. Lesson: leave the compute section compiler-scheduled.
//  R3: R1 gemm verbatim (71-75 us band) + sincos folded into prelude.
//  R4 (NEUTRAL): faithful 8-phase port (128x256, 8w, tri-buf, vmcnt(6),
//     setprio): 75.3 us, MfmaUtil 38%. Two very different schedules = same
//     perf -> shared-resource bound: per-wave 64x64 tile -> LDS read
//     0.5 KB/MFMA; LDS port demand ~75% of b128 ceiling; L2 30%, HBM 20%.
//     -> LDS-port-bound hypothesis.
//  R5 (NO DATA): container failed twice; kernel re-audited (no hang mode
//     found: uniform barriers, drainable vmcnt, in-bounds addrs, VGPR ok).
//  R6 (this): R5 resubmitted with hardened asm (early-clobber "=&v" on
//     A-load outputs); design unchanged: A operand global->VGPR direct
//     (asm dwordx4, prefetch-1, unified per-wave vmcnt queue with B glds:
//     vmcnt(12)); B keeps R1 LDS pipeline. LDS traffic/tile halves.

#define GK 4096      // inner dim (M in reference)
#define GN 4096      // output cols (N rows of W)
#define GT 2048      // tokens
#define NPAIR 2048   // S

typedef __bf16 bf16x8 __attribute__((ext_vector_type(8)));
typedef float  f32x4  __attribute__((ext_vector_type(4)));

static __device__ __forceinline__ unsigned short f2bf(float f) {
    union { float f; unsigned int u; } v; v.f = f;
    unsigned int r = v.u + 0x7fffu + ((v.u >> 16) & 1u);   // RNE
    return (unsigned short)(r >> 16);
}
static __device__ __forceinline__ unsigned int pack2bf(float a, float b) {
    return (unsigned int)f2bf(a) | ((unsigned int)f2bf(b) << 16);
}

// ---------------- Fused prelude ----------------
// blocks [0, 2048): build W_eff row pair s (bf16), single pass over W.
//   theta_R sincos computed inline (8 pairs/thread).
// blocks [2048, 4096): convert a 32 KB slice of x to bf16.
__global__ __launch_bounds__(256) void prelude(
    const float* __restrict__ W, const float* __restrict__ thL,
    const float* __restrict__ thR, const float* __restrict__ ecd,
    const float* __restrict__ x,
    unsigned short* __restrict__ Weff, unsigned short* __restrict__ Xbf)
{
    const int tid = threadIdx.x;

    if (blockIdx.x >= 2048) {
        // ---- x f32 -> bf16 ----
        const int cb = blockIdx.x - 2048;
        const size_t base = (size_t)cb * 512;             // 8-float chunk index
        const float4* X4 = (const float4*)x;
        uint4* O4 = (uint4*)Xbf;
#pragma unroll
        for (int k = 0; k < 2; k++) {
            const size_t m = base + tid + k * 256;
            const float4 a = X4[2 * m];
            const float4 b = X4[2 * m + 1];
            uint4 o;
            o.x = pack2bf(a.x, a.y);
            o.y = pack2bf(a.z, a.w);
            o.z = pack2bf(b.x, b.y);
            o.w = pack2bf(b.z, b.w);
            O4[m] = o;
        }
        return;
    }

    // ---- W_eff for row pair s ----
    const int s  = blockIdx.x;
    const int i0 = 2 * s, i1 = 2 * s + 1;

    const float tl = thL[s];
    const float cL = cosf(tl), sL = sinf(tl);

    float4 b0[4], b1[4];                        // rotated rows (held)
    float s00 = 0.f, s11 = 0.f, s01 = 0.f;      // ||w0||^2, ||w1||^2, <w0,w1>

    const float4* r0 = (const float4*)(W + (size_t)i0 * GK);
    const float4* r1 = (const float4*)(W + (size_t)i1 * GK);
    const float2* T2 = (const float2*)thR;      // (thR[2t], thR[2t+1]) per float4 of cols

#pragma unroll
    for (int k = 0; k < 4; k++) {
        const int c4 = tid + k * 256;           // float4 index: cols 4*c4 .. +3
        const float4 w0 = r0[c4];
        const float4 w1 = r1[c4];
        const float2 tt = T2[c4];               // thetas for col pairs 2*c4, 2*c4+1
        float4 cs;                              // cR0,sR0,cR1,sR1
        sincosf(tt.x, &cs.y, &cs.x);
        sincosf(tt.y, &cs.w, &cs.z);
        s00 += w0.x * w0.x + w0.y * w0.y + w0.z * w0.z + w0.w * w0.w;
        s11 += w1.x * w1.x + w1.y * w1.y + w1.z * w1.z + w1.w * w1.w;
        s01 += w0.x * w1.x + w0.y * w1.y + w0.z * w1.z + w0.w * w1.w;
        // left rotation (row mix)
        const float a0x = cL * w0.x - sL * w1.x;
        const float a0y = cL * w0.y - sL * w1.y;
        const float a0z = cL * w0.z - sL * w1.z;
        const float a0w = cL * w0.w - sL * w1.w;
        const float a1x = sL * w0.x + cL * w1.x;
        const float a1y = sL * w0.y + cL * w1.y;
        const float a1z = sL * w0.z + cL * w1.z;
        const float a1w = sL * w0.w + cL * w1.w;
        // right rotation (col mix within (x,y) and (z,w))
        b0[k].x = cs.x * a0x - cs.y * a0y;
        b0[k].y = cs.y * a0x + cs.x * a0y;
        b0[k].z = cs.z * a0z - cs.w * a0w;
        b0[k].w = cs.w * a0z + cs.z * a0w;
        b1[k].x = cs.x * a1x - cs.y * a1y;
        b1[k].y = cs.y * a1x + cs.x * a1y;
        b1[k].z = cs.z * a1z - cs.w * a1w;
        b1[k].w = cs.w * a1z + cs.z * a1w;
    }

    // block reduction of 3 sums
#pragma unroll
    for (int off = 32; off; off >>= 1) {
        s00 += __shfl_down(s00, off);
        s11 += __shfl_down(s11, off);
        s01 += __shfl_down(s01, off);
    }
    __shared__ float red[3][4];
    __shared__ float scales[2];
    const int wave = tid >> 6, lane = tid & 63;
    if (lane == 0) { red[0][wave] = s00; red[1][wave] = s11; red[2][wave] = s01; }
    __syncthreads();
    if (tid == 0) {
        const float t0 = red[0][0] + red[0][1] + red[0][2] + red[0][3];
        const float t1 = red[1][0] + red[1][1] + red[1][2] + red[1][3];
        const float td = red[2][0] + red[2][1] + red[2][2] + red[2][3];
        // rotated row norms, analytic (right rotations preserve row norms)
        const float n0 = cL * cL * t0 + sL * sL * t1 - 2.f * cL * sL * td;
        const float n1 = sL * sL * t0 + cL * cL * t1 + 2.f * cL * sL * td;
        scales[0] = sqrtf(t0) * expf(ecd[i0]) / (sqrtf(n0) + 1e-8f);
        scales[1] = sqrtf(t1) * expf(ecd[i1]) / (sqrtf(n1) + 1e-8f);
    }
    __syncthreads();
    const float sc0 = scales[0], sc1 = scales[1];

    uint2* o0 = (uint2*)(Weff + (size_t)i0 * GK);   // 4 bf16 = 8B per float4
    uint2* o1 = (uint2*)(Weff + (size_t)i1 * GK);
#pragma unroll
    for (int k = 0; k < 4; k++) {
        const int c4 = tid + k * 256;
        uint2 p0, p1;
        p0.x = pack2bf(b0[k].x * sc0, b0[k].y * sc0);
        p0.y = pack2bf(b0[k].z * sc0, b0[k].w * sc0);
        p1.x = pack2bf(b1[k].x * sc1, b1[k].y * sc1);
        p1.y = pack2bf(b1[k].z * sc1, b1[k].w * sc1);
        o0[c4] = p0;
        o1[c4] = p1;
    }
}

// ---------------- GEMM  out = Xbf @ Weff^T + bias ----------------
// R6 structure: A global->VGPR direct, B via R1's LDS pipeline.
//   128x128 tile, BK=64, 4 waves (2x2), per-wave 64x64, grid 512 = 2/CU.
//   B: dbuf LDS (32 KB), 4 glds16/tile, T2 both-sides swizzle, prefetch-1.
//   A: 8 asm global_load_dwordx4 per wave per tile into registers,
//      prefetch-1 (ping-pong reg sets, statically indexed via 2x unroll).
//   One per-wave vmcnt queue: per tile issue {4 glds, 8 A-loads} = 12;
//   s_waitcnt vmcnt(12) drains tile t while t+1 stays in flight
//   (vmcnt waits for the (outstanding-N) OLDEST ops; all vmem ops share
//   one per-wave counter).
//   Compute section compiler-scheduled (R2 lesson: do not pin).
//   LDS traffic/tile/block: 48 KB vs R1's 96 KB (A reads+writes removed).
static __device__ __forceinline__ void glds16(const unsigned short* g, unsigned short* l) {
    __builtin_amdgcn_global_load_lds(
        (const __attribute__((address_space(1))) unsigned int*)g,
        (__attribute__((address_space(3))) unsigned int*)l, 16, 0, 0);
}

__global__ __launch_bounds__(256, 2) void gemm_bt(
    const unsigned short* __restrict__ A,   // (GT, GK) bf16
    const unsigned short* __restrict__ B,   // (GN, GK) bf16
    const float* __restrict__ bias,
    float* __restrict__ C)                  // (GT, GN) f32
{
    constexpr int BM = 128, BN = 128, BK = 64;
    constexpr int NT = GK / BK;                 // 64 K-tiles
    __shared__ unsigned short Bs[2][BN * BK];   // 2 x 16 KB

    const int tid  = threadIdx.x;
    const int lane = tid & 63;
    const int wave = tid >> 6;
    const int quad = lane >> 4;
    const int l16  = lane & 15;
    const int wm   = wave >> 1;     // 0..1
    const int wn   = wave & 1;      // 0..1
    const int bm   = blockIdx.y * BM;
    const int bn   = blockIdx.x * BN;
    // grid (32,16) x-major: blocks sharing bn land on the same XCD
    // (flat%8 == x%8 since 32%8==0) -> B panels are XCD-L2-local already.

    // ---- B staging addressing (R1, unchanged) ----
    // One glds16 per wave covers 8 rows of 128B. Swizzle: physical 16B
    // slot p of row r holds logical slot p ^ (r&7) => lane fetches global
    // slot (l&7)^lrow; LDS dest stays linear.
    const int lrow = lane >> 3;
    const int jlog = (lane & 7) ^ lrow;
    const unsigned short* gB[4];
    int loffB[4];
#pragma unroll
    for (int j = 0; j < 4; j++) {
        const int c = j * 4 + wave;             // 16 chunks of 8 rows
        gB[j] = B + (size_t)(bn + c * 8 + lrow) * GK + jlog * 8;
        loffB[j] = c * 512 + lane * 8;
    }

    // ---- A per-lane fragment base pointers (global->reg, no swizzle) ----
    // Fragment (i,kk): lane reads 16B at row bm+wm*64+i*16+l16,
    // col t*64 + kk*32 + quad*8.
    const unsigned short* Arow[4];
#pragma unroll
    for (int i = 0; i < 4; i++)
        Arow[i] = A + (size_t)(bm + wm * 64 + i * 16 + l16) * GK + quad * 8;

#define STAGE_B(buf, k0) do {                                             \
    _Pragma("unroll")                                                     \
    for (int j = 0; j < 4; j++)                                           \
        glds16(gB[j] + (k0), &Bs[buf][loffB[j]]);                         \
    } while (0)

#define A_LOADS(dst, k0) do {                                             \
    _Pragma("unroll")                                                     \
    for (int i = 0; i < 4; i++) {                                         \
        asm volatile("global_load_dwordx4 %0, %1, off"                    \
            : "=&v"(dst[0][i]) : "v"(Arow[i] + (k0)));                    \
        asm volatile("global_load_dwordx4 %0, %1, off"                    \
            : "=&v"(dst[1][i]) : "v"(Arow[i] + (k0) + 32));               \
    } } while (0)

    f32x4 acc[4][4] = {};

    // compute section: compiler-scheduled ds_read/MFMA interleave (R2
    // lesson). B fragment physical slot = (quad+4*kk) ^ (l16&7).
#define COMPUTE(buf, aF) do {                                             \
    bf16x8 bF[2][4];                                                      \
    _Pragma("unroll")                                                     \
    for (int kk = 0; kk < 2; kk++) {                                      \
        const int ps = ((quad + 4 * kk) ^ (l16 & 7)) * 8;                 \
        _Pragma("unroll")                                                 \
        for (int j = 0; j < 4; j++)                                       \
            bF[kk][j] = *(const bf16x8*)&Bs[buf][(wn * 64 + j * 16 + l16) * BK + ps]; \
    }                                                                     \
    _Pragma("unroll")                                                     \
    for (int i = 0; i < 4; i++)                                           \
        _Pragma("unroll")                                                 \
        for (int j = 0; j < 4; j++) {                                     \
            acc[i][j] = __builtin_amdgcn_mfma_f32_16x16x32_bf16(          \
                aF[0][i], bF[0][j], acc[i][j], 0, 0, 0);                  \
            acc[i][j] = __builtin_amdgcn_mfma_f32_16x16x32_bf16(          \
                aF[1][i], bF[1][j], acc[i][j], 0, 0, 0);                  \
        }                                                                 \
    } while (0)

    // wait for tile t (oldest 12 of 24 in queue), all waves' B visible
#define WAIT12_BAR do {                                                   \
    __builtin_amdgcn_sched_barrier(0);                                    \
    asm volatile("s_waitcnt vmcnt(12)" ::: "memory");                     \
    __builtin_amdgcn_sched_barrier(0);                                    \
    __builtin_amdgcn_s_barrier();                                         \
    __builtin_amdgcn_sched_barrier(0);                                    \
    } while (0)

#define END_BAR do {                                                      \
    __builtin_amdgcn_sched_barrier(0);                                    \
    __builtin_amdgcn_s_barrier();                                         \
    } while (0)

    bf16x8 aX[2][4], aY[2][4];                  // ping-pong A register sets

    // prologue: tile 0 in flight (12 ops)
    STAGE_B(0, 0);
    A_LOADS(aX, 0);

    // main loop: tiles t (buf0/aX) and t+1 (buf1/aY), prefetching t+1, t+2
    for (int t = 0; t < NT - 2; t += 2) {
        STAGE_B(1, (t + 1) * BK);               // tile t+1 -> buf1
        A_LOADS(aY, (t + 1) * BK);
        WAIT12_BAR;                             // tile t resident
        COMPUTE(0, aX);
        END_BAR;                                // buf0 safe to re-stage

        STAGE_B(0, (t + 2) * BK);               // tile t+2 -> buf0
        A_LOADS(aX, (t + 2) * BK);
        WAIT12_BAR;                             // tile t+1 resident
        COMPUTE(1, aY);
        END_BAR;                                // buf1 safe to re-stage
    }
    // tail: tile 62 resident in buf0/aX; prefetch 63, compute 62, drain 63
    STAGE_B(1, (NT - 1) * BK);
    A_LOADS(aY, (NT - 1) * BK);
    WAIT12_BAR;
    COMPUTE(0, aX);
    END_BAR;

    __builtin_amdgcn_sched_barrier(0);
    asm volatile("s_waitcnt vmcnt(0)" ::: "memory");
    __builtin_amdgcn_sched_barrier(0);
    __builtin_amdgcn_s_barrier();
    __builtin_amdgcn_sched_barrier(0);
    COMPUTE(1, aY);

#undef STAGE_B
#undef A_LOADS
#undef COMPUTE
#undef WAIT12_BAR
#undef END_BAR

    // epilogue: C/D layout col=lane&15, row=quad*4+reg   (m89/m91 verified)
#pragma unroll
    for (int i = 0; i < 4; i++) {
        const int m = bm + wm * 64 + i * 16 + quad * 4;
#pragma unroll
        for (int j = 0; j < 4; j++) {
            const int n = bn + wn * 64 + j * 16 + l16;
            const float bv = bias[n];
#pragma unroll
            for (int r = 0; r < 4; r++)
                C[(size_t)(m + r) * GN + n] = acc[i][j][r] + bv;
        }
    }
}

extern "C" void kernel_launch(void* const* d_in, const int* in_sizes, int n_in,
                              void* d_out, int out_size, void* d_ws, size_t ws_size,
                              hipStream_t stream) {
    const float* x    = (const float*)d_in[0];
    const float* W    = (const float*)d_in[1];
    const float* bias = (const float*)d_in[2];
    const float* thL  = (const float*)d_in[3];
    const float* thR  = (const float*)d_in[4];
    const float* ecd  = (const float*)d_in[5];
    // pairs_L / pairs_R (d_in[6], d_in[7]) are fixed arange reshapes:
    // pair s = (2s, 2s+1) — exploited structurally above.

    unsigned short* Weff = (unsigned short*)d_ws;                                // 32 MB
    unsigned short* Xbf  = (unsigned short*)((char*)d_ws + (size_t)GN * GK * 2); // 16 MB

    float* out = (float*)d_out;

    prelude<<<dim3(4096), dim3(256), 0, stream>>>(W, thL, thR, ecd, x, Weff, Xbf);
    gemm_bt<<<dim3(GN / 128, GT / 128), dim3(256), 0, stream>>>(Xbf, Weff, bias, out);
}

// Round 7
// 210.807 us; speedup vs baseline: 1.3160x; 1.3160x over previous
//
#include <hip/hip_runtime.h>
#include <hip/hip_bf16.h>

// Problem: out = x @ W_eff^T + bias   (TOKENS=2048, N=4096, M=K=4096)
// W_eff = rownorm-rescaled Givens-rotated W; pairs are (2s,2s+1) adjacent,
// so row pair (2s,2s+1) and col pair (2t,2t+1) are closed 2x2 blocks.
//
// Norm identity: right rotations are orthogonal on the column space ->
// preserve each row's norm. So ||Wp row|| needs only ||w0||^2, ||w1||^2,
// <w0,w1> (3 reduced scalars), not the rotated data.
//
// Journal:
//  R1 (good): 128x128 BK=64 dbuf + counted vmcnt(8) + T2 both-sides swizzle:
//     gemm 95.3 -> 71.4 us (962 TF, MfmaUtil 40%, bank conflicts 0).
//  R2 (FAILED): phase split w/ lgkm(0) drains between ds_read and MFMA:
//     107 us. Lesson: leave the compute section compiler-scheduled.
//  R3: R1 gemm verbatim (71-75 us band) + sincos folded into prelude.
//  R4 (NEUTRAL): faithful phase-template port (128x256, 8w, tri-buf,
//     vmcnt(6), setprio): 75.3 us. Two very different schedules = same
//     perf -> shared-resource bound; LDS traffic identical in both ->
//     LDS-port-bound hypothesis.
//  R5 (NO DATA): container failed twice.
//  R6 (REGRESSION 144.6 us, CONFOUNDED): A global->reg with row-major A:
//     fragment loads = 16 scattered lines/wave (4x TA requests) ->
//     request-rate-bound (MfmaUtil 18.7, HBM 11%). LDS theory NOT tested.
//     Loop skeleton (vmcnt(12) queue, ping-pong regs) verified correct.
//  R7 (this): clean test: A stored FRAGMENT-MAJOR by the prelude
//     (chunk c = (((I*64+t)*2+kk)*4+q)*16+r holds A[16I+r][64t+32kk+8q+e])
//     so gemm's A loads are base+lane*16B = contiguous 1KB/instr, no LDS.
//     B keeps R1 LDS pipeline. Gemm LDS traffic/tile: 96 -> 48 KB.

#define GK 4096      // inner dim (M in reference)
#define GN 4096      // output cols (N rows of W)
#define GT 2048      // tokens
#define NPAIR 2048   // S

typedef __bf16 bf16x8 __attribute__((ext_vector_type(8)));
typedef float  f32x4  __attribute__((ext_vector_type(4)));

static __device__ __forceinline__ unsigned short f2bf(float f) {
    union { float f; unsigned int u; } v; v.f = f;
    unsigned int r = v.u + 0x7fffu + ((v.u >> 16) & 1u);   // RNE
    return (unsigned short)(r >> 16);
}
static __device__ __forceinline__ unsigned int pack2bf(float a, float b) {
    return (unsigned int)f2bf(a) | ((unsigned int)f2bf(b) << 16);
}

// ---------------- Fused prelude ----------------
// blocks [0, 2048): build W_eff row pair s (bf16, row-major), single pass.
//   theta_R sincos computed inline (8 pairs/thread).
// blocks [2048, 4096): convert x to bf16 in FRAGMENT-MAJOR layout:
//   16B chunk c: r=c&15, q=(c>>4)&3, kk=(c>>6)&1, t=(c>>7)&63, I=c>>13
//   holds x[16I+r][64t+32kk+8q .. +7].  Writes coalesced (linear in c);
//   reads cover 16 rows x 128B full lines per wave.
__global__ __launch_bounds__(256) void prelude(
    const float* __restrict__ W, const float* __restrict__ thL,
    const float* __restrict__ thR, const float* __restrict__ ecd,
    const float* __restrict__ x,
    unsigned short* __restrict__ Weff, unsigned short* __restrict__ Xbf)
{
    const int tid = threadIdx.x;

    if (blockIdx.x >= 2048) {
        // ---- x f32 -> bf16, fragment-major permute ----
        const int cb = blockIdx.x - 2048;
        const float4* X4 = (const float4*)x;
        uint4* O4 = (uint4*)Xbf;
#pragma unroll
        for (int k = 0; k < 2; k++) {
            const int c  = cb * 512 + tid + k * 256;   // 16B chunk index
            const int r  = c & 15;
            const int q  = (c >> 4) & 3;
            const int kk = (c >> 6) & 1;
            const int t  = (c >> 7) & 63;
            const int I  = c >> 13;
            const int m  = I * 16 + r;                 // token row
            const int k4 = t * 16 + kk * 8 + q * 2;    // float4 col index
            const float4 a = X4[(size_t)m * (GK / 4) + k4];
            const float4 b = X4[(size_t)m * (GK / 4) + k4 + 1];
            uint4 o;
            o.x = pack2bf(a.x, a.y);
            o.y = pack2bf(a.z, a.w);
            o.z = pack2bf(b.x, b.y);
            o.w = pack2bf(b.z, b.w);
            O4[c] = o;
        }
        return;
    }

    // ---- W_eff for row pair s (row-major, unchanged) ----
    const int s  = blockIdx.x;
    const int i0 = 2 * s, i1 = 2 * s + 1;

    const float tl = thL[s];
    const float cL = cosf(tl), sL = sinf(tl);

    float4 b0[4], b1[4];                        // rotated rows (held)
    float s00 = 0.f, s11 = 0.f, s01 = 0.f;      // ||w0||^2, ||w1||^2, <w0,w1>

    const float4* r0 = (const float4*)(W + (size_t)i0 * GK);
    const float4* r1 = (const float4*)(W + (size_t)i1 * GK);
    const float2* T2 = (const float2*)thR;      // (thR[2t], thR[2t+1]) per float4 of cols

#pragma unroll
    for (int k = 0; k < 4; k++) {
        const int c4 = tid + k * 256;           // float4 index: cols 4*c4 .. +3
        const float4 w0 = r0[c4];
        const float4 w1 = r1[c4];
        const float2 tt = T2[c4];               // thetas for col pairs 2*c4, 2*c4+1
        float4 cs;                              // cR0,sR0,cR1,sR1
        sincosf(tt.x, &cs.y, &cs.x);
        sincosf(tt.y, &cs.w, &cs.z);
        s00 += w0.x * w0.x + w0.y * w0.y + w0.z * w0.z + w0.w * w0.w;
        s11 += w1.x * w1.x + w1.y * w1.y + w1.z * w1.z + w1.w * w1.w;
        s01 += w0.x * w1.x + w0.y * w1.y + w0.z * w1.z + w0.w * w1.w;
        // left rotation (row mix)
        const float a0x = cL * w0.x - sL * w1.x;
        const float a0y = cL * w0.y - sL * w1.y;
        const float a0z = cL * w0.z - sL * w1.z;
        const float a0w = cL * w0.w - sL * w1.w;
        const float a1x = sL * w0.x + cL * w1.x;
        const float a1y = sL * w0.y + cL * w1.y;
        const float a1z = sL * w0.z + cL * w1.z;
        const float a1w = sL * w0.w + cL * w1.w;
        // right rotation (col mix within (x,y) and (z,w))
        b0[k].x = cs.x * a0x - cs.y * a0y;
        b0[k].y = cs.y * a0x + cs.x * a0y;
        b0[k].z = cs.z * a0z - cs.w * a0w;
        b0[k].w = cs.w * a0z + cs.z * a0w;
        b1[k].x = cs.x * a1x - cs.y * a1y;
        b1[k].y = cs.y * a1x + cs.x * a1y;
        b1[k].z = cs.z * a1z - cs.w * a1w;
        b1[k].w = cs.w * a1z + cs.z * a1w;
    }

    // block reduction of 3 sums
#pragma unroll
    for (int off = 32; off; off >>= 1) {
        s00 += __shfl_down(s00, off);
        s11 += __shfl_down(s11, off);
        s01 += __shfl_down(s01, off);
    }
    __shared__ float red[3][4];
    __shared__ float scales[2];
    const int wave = tid >> 6, lane = tid & 63;
    if (lane == 0) { red[0][wave] = s00; red[1][wave] = s11; red[2][wave] = s01; }
    __syncthreads();
    if (tid == 0) {
        const float t0 = red[0][0] + red[0][1] + red[0][2] + red[0][3];
        const float t1 = red[1][0] + red[1][1] + red[1][2] + red[1][3];
        const float td = red[2][0] + red[2][1] + red[2][2] + red[2][3];
        // rotated row norms, analytic (right rotations preserve row norms)
        const float n0 = cL * cL * t0 + sL * sL * t1 - 2.f * cL * sL * td;
        const float n1 = sL * sL * t0 + cL * cL * t1 + 2.f * cL * sL * td;
        scales[0] = sqrtf(t0) * expf(ecd[i0]) / (sqrtf(n0) + 1e-8f);
        scales[1] = sqrtf(t1) * expf(ecd[i1]) / (sqrtf(n1) + 1e-8f);
    }
    __syncthreads();
    const float sc0 = scales[0], sc1 = scales[1];

    uint2* o0 = (uint2*)(Weff + (size_t)i0 * GK);   // 4 bf16 = 8B per float4
    uint2* o1 = (uint2*)(Weff + (size_t)i1 * GK);
#pragma unroll
    for (int k = 0; k < 4; k++) {
        const int c4 = tid + k * 256;
        uint2 p0, p1;
        p0.x = pack2bf(b0[k].x * sc0, b0[k].y * sc0);
        p0.y = pack2bf(b0[k].z * sc0, b0[k].w * sc0);
        p1.x = pack2bf(b1[k].x * sc1, b1[k].y * sc1);
        p1.y = pack2bf(b1[k].z * sc1, b1[k].w * sc1);
        o0[c4] = p0;
        o1[c4] = p1;
    }
}

// ---------------- GEMM  out = Xbf @ Weff^T + bias ----------------
// R7 structure: A fragment-major global->VGPR (coalesced 1KB/instr),
//   B via R1's LDS pipeline.  128x128 tile, BK=64, 4 waves (2x2),
//   per-wave 64x64, grid 512 = 2/CU.
//   B: dbuf LDS (32 KB), 4 glds16/tile, T2 both-sides swizzle, prefetch-1.
//   A: 8 asm global_load_dwordx4 per thread per tile, base + lane*16B
//      contiguous (fragment-major layout), prefetch-1 ping-pong reg sets.
//   Unified per-wave vmcnt queue: {4 glds, 8 A-loads} = 12 per tile;
//   s_waitcnt vmcnt(12) drains tile t while t+1 stays in flight.
//   Compute section compiler-scheduled (R2 lesson).
//   Gemm LDS traffic/tile/block: 48 KB (B only) vs R1's 96 KB.
static __device__ __forceinline__ void glds16(const unsigned short* g, unsigned short* l) {
    __builtin_amdgcn_global_load_lds(
        (const __attribute__((address_space(1))) unsigned int*)g,
        (__attribute__((address_space(3))) unsigned int*)l, 16, 0, 0);
}

__global__ __launch_bounds__(256, 2) void gemm_bt(
    const unsigned short* __restrict__ A,   // fragment-major Xbf (see prelude)
    const unsigned short* __restrict__ B,   // (GN, GK) bf16 row-major
    const float* __restrict__ bias,
    float* __restrict__ C)                  // (GT, GN) f32
{
    constexpr int BM = 128, BN = 128, BK = 64;
    constexpr int NT = GK / BK;                 // 64 K-tiles
    __shared__ unsigned short Bs[2][BN * BK];   // 2 x 16 KB

    const int tid  = threadIdx.x;
    const int lane = tid & 63;
    const int wave = tid >> 6;
    const int quad = lane >> 4;
    const int l16  = lane & 15;
    const int wm   = wave >> 1;     // 0..1
    const int wn   = wave & 1;      // 0..1
    const int bm   = blockIdx.y * BM;
    const int bn   = blockIdx.x * BN;
    // grid (32,16) x-major: blocks sharing bn land on the same XCD
    // (flat%8 == x%8 since 32%8==0) -> B panels are XCD-L2-local already.

    // ---- B staging addressing (R1, unchanged) ----
    // One glds16 per wave covers 8 rows of 128B. Swizzle: physical 16B
    // slot p of row r holds logical slot p ^ (r&7) => lane fetches global
    // slot (l&7)^lrow; LDS dest stays linear.
    const int lrow = lane >> 3;
    const int jlog = (lane & 7) ^ lrow;
    const unsigned short* gB[4];
    int loffB[4];
#pragma unroll
    for (int j = 0; j < 4; j++) {
        const int c = j * 4 + wave;             // 16 chunks of 8 rows
        gB[j] = B + (size_t)(bn + c * 8 + lrow) * GK + jlog * 8;
        loffB[j] = c * 512 + lane * 8;
    }

    // ---- A fragment-major base pointers ----
    // I-block (16 rows) i of this wave: I = blockIdx.y*8 + wm*4 + i.
    // Per I-block: NT*2*512 = 65536 bf16 (128 KB). Fragment (t,kk):
    // offset t*1024 + kk*512 + lane*8  (lane = quad*16 + l16 matches the
    // MFMA A layout: row = l16, k-group = quad).  Contiguous per wave.
    const unsigned short* Afrag[4];
#pragma unroll
    for (int i = 0; i < 4; i++)
        Afrag[i] = A + (size_t)(blockIdx.y * 8 + wm * 4 + i) * 65536 + lane * 8;

#define STAGE_B(buf, k0) do {                                             \
    _Pragma("unroll")                                                     \
    for (int j = 0; j < 4; j++)                                           \
        glds16(gB[j] + (k0), &Bs[buf][loffB[j]]);                         \
    } while (0)

#define A_LOADS(dst, t) do {                                              \
    _Pragma("unroll")                                                     \
    for (int i = 0; i < 4; i++) {                                         \
        asm volatile("global_load_dwordx4 %0, %1, off"                    \
            : "=&v"(dst[0][i]) : "v"(Afrag[i] + (t) * 1024));             \
        asm volatile("global_load_dwordx4 %0, %1, off"                    \
            : "=&v"(dst[1][i]) : "v"(Afrag[i] + (t) * 1024 + 512));       \
    } } while (0)

    f32x4 acc[4][4] = {};

    // compute section: compiler-scheduled ds_read/MFMA interleave (R2
    // lesson). B fragment physical slot = (quad+4*kk) ^ (l16&7).
#define COMPUTE(buf, aF) do {                                             \
    bf16x8 bF[2][4];                                                      \
    _Pragma("unroll")                                                     \
    for (int kk = 0; kk < 2; kk++) {                                      \
        const int ps = ((quad + 4 * kk) ^ (l16 & 7)) * 8;                 \
        _Pragma("unroll")                                                 \
        for (int j = 0; j < 4; j++)                                       \
            bF[kk][j] = *(const bf16x8*)&Bs[buf][(wn * 64 + j * 16 + l16) * BK + ps]; \
    }                                                                     \
    _Pragma("unroll")                                                     \
    for (int i = 0; i < 4; i++)                                           \
        _Pragma("unroll")                                                 \
        for (int j = 0; j < 4; j++) {                                     \
            acc[i][j] = __builtin_amdgcn_mfma_f32_16x16x32_bf16(          \
                aF[0][i], bF[0][j], acc[i][j], 0, 0, 0);                  \
            acc[i][j] = __builtin_amdgcn_mfma_f32_16x16x32_bf16(          \
                aF[1][i], bF[1][j], acc[i][j], 0, 0, 0);                  \
        }                                                                 \
    } while (0)

    // wait for tile t (oldest 12 of 24 in queue), all waves' B visible
#define WAIT12_BAR do {                                                   \
    __builtin_amdgcn_sched_barrier(0);                                    \
    asm volatile("s_waitcnt vmcnt(12)" ::: "memory");                     \
    __builtin_amdgcn_sched_barrier(0);                                    \
    __builtin_amdgcn_s_barrier();                                         \
    __builtin_amdgcn_sched_barrier(0);                                    \
    } while (0)

#define END_BAR do {                                                      \
    __builtin_amdgcn_sched_barrier(0);                                    \
    __builtin_amdgcn_s_barrier();                                         \
    } while (0)

    bf16x8 aX[2][4], aY[2][4];                  // ping-pong A register sets

    // prologue: tile 0 in flight (12 ops)
    STAGE_B(0, 0);
    A_LOADS(aX, 0);

    // main loop: tiles t (buf0/aX) and t+1 (buf1/aY), prefetching t+1, t+2
    for (int t = 0; t < NT - 2; t += 2) {
        STAGE_B(1, (t + 1) * BK);               // tile t+1 -> buf1
        A_LOADS(aY, t + 1);
        WAIT12_BAR;                             // tile t resident
        COMPUTE(0, aX);
        END_BAR;                                // buf0 safe to re-stage

        STAGE_B(0, (t + 2) * BK);               // tile t+2 -> buf0
        A_LOADS(aX, t + 2);
        WAIT12_BAR;                             // tile t+1 resident
        COMPUTE(1, aY);
        END_BAR;                                // buf1 safe to re-stage
    }
    // tail: tile 62 resident in buf0/aX; prefetch 63, compute 62, drain 63
    STAGE_B(1, (NT - 1) * BK);
    A_LOADS(aY, NT - 1);
    WAIT12_BAR;
    COMPUTE(0, aX);
    END_BAR;

    __builtin_amdgcn_sched_barrier(0);
    asm volatile("s_waitcnt vmcnt(0)" ::: "memory");
    __builtin_amdgcn_sched_barrier(0);
    __builtin_amdgcn_s_barrier();
    __builtin_amdgcn_sched_barrier(0);
    COMPUTE(1, aY);

#undef STAGE_B
#undef A_LOADS
#undef COMPUTE
#undef WAIT12_BAR
#undef END_BAR

    // epilogue: C/D layout col=lane&15, row=quad*4+reg   (m89/m91 verified)
#pragma unroll
    for (int i = 0; i < 4; i++) {
        const int m = bm + wm * 64 + i * 16 + quad * 4;
#pragma unroll
        for (int j = 0; j < 4; j++) {
            const int n = bn + wn * 64 + j * 16 + l16;
            const float bv = bias[n];
#pragma unroll
            for (int r = 0; r < 4; r++)
                C[(size_t)(m + r) * GN + n] = acc[i][j][r] + bv;
        }
    }
}

extern "C" void kernel_launch(void* const* d_in, const int* in_sizes, int n_in,
                              void* d_out, int out_size, void* d_ws, size_t ws_size,
                              hipStream_t stream) {
    const float* x    = (const float*)d_in[0];
    const float* W    = (const float*)d_in[1];
    const float* bias = (const float*)d_in[2];
    const float* thL  = (const float*)d_in[3];
    const float* thR  = (const float*)d_in[4];
    const float* ecd  = (const float*)d_in[5];
    // pairs_L / pairs_R (d_in[6], d_in[7]) are fixed arange reshapes:
    // pair s = (2s, 2s+1) — exploited structurally above.

    unsigned short* Weff = (unsigned short*)d_ws;                                // 32 MB
    unsigned short* Xbf  = (unsigned short*)((char*)d_ws + (size_t)GN * GK * 2); // 16 MB (fragment-major)

    float* out = (float*)d_out;

    prelude<<<dim3(4096), dim3(256), 0, stream>>>(W, thL, thR, ecd, x, Weff, Xbf);
    gemm_bt<<<dim3(GN / 128, GT / 128), dim3(256), 0, stream>>>(Xbf, Weff, bias, out);
}